// Round 11
// baseline (297.737 us; speedup 1.0000x reference)
//
#include <hip/hip_runtime.h>
#include <math.h>

#define D_DIM 2048
#define R_DIM 512
#define E_NUM 8
#define B_NUM 8
#define S_NUM 2048
#define M_DIM 16384
#define LN_EPS 1e-5f

typedef __attribute__((ext_vector_type(8))) short bf16x8;
typedef __attribute__((ext_vector_type(4))) float f32x4;

// Manual RNE float->bf16 (inputs finite/normal; no NaN path needed)
__device__ __forceinline__ unsigned short f2bf(float f) {
    unsigned u = __float_as_uint(f);
    return (unsigned short)((u + 0x7FFFu + ((u >> 16) & 1u)) >> 16);
}

__device__ __forceinline__ void gload_lds16(const void* g, void* l) {
    __builtin_amdgcn_global_load_lds(
        (const __attribute__((address_space(1))) void*)g,
        (__attribute__((address_space(3))) void*)l, 16, 0, 0);
}

// ---------------------------------------------------------------------------
// Fused prep kernel, one dispatch:
//   [0, 16384):        per-token LayerNorm -> bf16 in place (first 4KB/row)
//   [16384, 17408):    w1[k][n] fp32 -> wT[n][k] bf16 (transpose + round)
//   [17408, 17472):    W2R[r][e] = sum_q w2[r][q]*wr[q][e]   (8 rows/block)
//   17472:             c2[e] = S*sum_q b2[q]*wr[q][e] + br[e];  zero ticket cnt
//   [17473, 17489):    zero hsum (4096 floats)
// W2R/c2 have no GEMM dependency -> hidden under the BW-bound LN phase.
// ---------------------------------------------------------------------------
__global__ __launch_bounds__(256) void prep_kernel(float* __restrict__ x,
                                                   const float* __restrict__ gamma,
                                                   const float* __restrict__ beta,
                                                   const float* __restrict__ w1,
                                                   const float* __restrict__ w2,
                                                   const float* __restrict__ b2,
                                                   const float* __restrict__ wr,
                                                   const float* __restrict__ br,
                                                   unsigned short* __restrict__ wt,
                                                   float* __restrict__ w2r,
                                                   float* __restrict__ c2,
                                                   float* __restrict__ hsum,
                                                   int* __restrict__ cnt) {
    const int t = threadIdx.x;
    if (blockIdx.x < M_DIM) {
        // ---- LayerNorm + bf16 pack, in place ----
        __shared__ float sred[8];
        float* row = x + (size_t)blockIdx.x * D_DIM;
        const float4 v0  = ((const float4*)row)[t];
        const float4 v1  = ((const float4*)row)[t + 256];
        const float4 g0  = ((const float4*)gamma)[t];
        const float4 g1  = ((const float4*)gamma)[t + 256];
        const float4 be0 = ((const float4*)beta)[t];
        const float4 be1 = ((const float4*)beta)[t + 256];

        float s  = v0.x + v0.y + v0.z + v0.w + v1.x + v1.y + v1.z + v1.w;
        float sq = v0.x*v0.x + v0.y*v0.y + v0.z*v0.z + v0.w*v0.w
                 + v1.x*v1.x + v1.y*v1.y + v1.z*v1.z + v1.w*v1.w;
#pragma unroll
        for (int off = 32; off > 0; off >>= 1) {
            s  += __shfl_down(s, off);
            sq += __shfl_down(sq, off);
        }
        if ((t & 63) == 0) { sred[(t >> 6) * 2] = s; sred[(t >> 6) * 2 + 1] = sq; }
        __syncthreads();            // also: all reads of `row` are complete
        s  = sred[0] + sred[2] + sred[4] + sred[6];
        sq = sred[1] + sred[3] + sred[5] + sred[7];
        const float mu  = s * (1.f / D_DIM);
        const float var = sq * (1.f / D_DIM) - mu * mu;
        const float rs  = rsqrtf(var + LN_EPS);

        ushort4 h0, h1;
        h0.x = f2bf(fmaf((v0.x - mu) * rs, g0.x, be0.x));
        h0.y = f2bf(fmaf((v0.y - mu) * rs, g0.y, be0.y));
        h0.z = f2bf(fmaf((v0.z - mu) * rs, g0.z, be0.z));
        h0.w = f2bf(fmaf((v0.w - mu) * rs, g0.w, be0.w));
        h1.x = f2bf(fmaf((v1.x - mu) * rs, g1.x, be1.x));
        h1.y = f2bf(fmaf((v1.y - mu) * rs, g1.y, be1.y));
        h1.z = f2bf(fmaf((v1.z - mu) * rs, g1.z, be1.z));
        h1.w = f2bf(fmaf((v1.w - mu) * rs, g1.w, be1.w));

        ushort4* rowu = (ushort4*)row;
        rowu[t]       = h0;          // k = 4t .. 4t+3
        rowu[t + 256] = h1;          // k = 1024+4t ..
    } else if (blockIdx.x < M_DIM + 1024) {
        // ---- w1 transpose + bf16 round: wT[n][k] ----
        const int tid = (blockIdx.x - M_DIM) * 256 + t;   // 262144 = 512 n * 512 k4
        const int n  = tid >> 9;
        const int k4 = tid & 511;
        ushort4 h;
        h.x = f2bf(w1[(size_t)(k4 * 4 + 0) * R_DIM + n]);
        h.y = f2bf(w1[(size_t)(k4 * 4 + 1) * R_DIM + n]);
        h.z = f2bf(w1[(size_t)(k4 * 4 + 2) * R_DIM + n]);
        h.w = f2bf(w1[(size_t)(k4 * 4 + 3) * R_DIM + n]);
        ((ushort4*)wt)[(size_t)n * 512 + k4] = h;
    } else if (blockIdx.x < M_DIM + 1024 + 64) {
        // ---- W2R: 8 r-rows per block ----
        __shared__ float wrt[E_NUM * R_DIM];   // wrT[e][q], 16KB
        for (int i = 0; i < 16; ++i) {
            const int g = i * 256 + t;          // 4096 = 512q * 8e
            wrt[(g & 7) * R_DIM + (g >> 3)] = wr[g];
        }
        __syncthreads();
        const int bw = blockIdx.x - (M_DIM + 1024);
        const int r  = bw * 8 + (t >> 5);
        const int l  = t & 31;
        float acc[E_NUM] = {0, 0, 0, 0, 0, 0, 0, 0};
        for (int k = 0; k < 16; ++k) {
            const int q = l + 32 * k;
            const float wv = w2[(size_t)r * R_DIM + q];
#pragma unroll
            for (int e = 0; e < E_NUM; ++e)
                acc[e] = fmaf(wv, wrt[e * R_DIM + q], acc[e]);
        }
#pragma unroll
        for (int e = 0; e < E_NUM; ++e) {
#pragma unroll
            for (int off = 16; off > 0; off >>= 1)
                acc[e] += __shfl_down(acc[e], off, 32);
        }
        if (l == 0) {
#pragma unroll
            for (int e = 0; e < E_NUM; ++e) w2r[r * E_NUM + e] = acc[e];
        }
    } else if (blockIdx.x == M_DIM + 1024 + 64) {
        // ---- c2[e] = S * sum_q b2[q]*wr[q][e] + br[e]; zero ticket ----
        __shared__ float part[8][E_NUM];
        float s = 0.f;
        const int e = t & 7, qg = (t >> 3) & 7;
        if (t < 64) {
            for (int q = qg; q < R_DIM; q += 8)
                s = fmaf(b2[q], wr[q * E_NUM + e], s);
            part[qg][e] = s;
        }
        if (t == 128) *cnt = 0;
        __syncthreads();
        if (t < E_NUM) {
            float v = 0.f;
#pragma unroll
            for (int g = 0; g < 8; ++g) v += part[g][t];
            c2[t] = fmaf((float)S_NUM, v, br[t]);
        }
    } else {
        // ---- zero hsum (4096 floats) ----
        hsum[(blockIdx.x - (M_DIM + 1024 + 65)) * 256 + t] = 0.f;
    }
}

// ---------------------------------------------------------------------------
// Main GEMM + fused finish (split-K ticket pattern):
// C[16384][512] = xn @ wT^T, bf16 MFMA, 2-phase double-buffered schedule
// (unchanged from r10's measured kernel). Epilogue: +b1, exact GELU,
// column-sum -> atomicAdd hsum. Then LAST block (ticket 511) computes
// logits = hsum @ W2R + c2, BCE loss, argmax counts, mode -> out.
// ---------------------------------------------------------------------------
#define BM 128
#define BN 128
#define BK 64

__global__ __launch_bounds__(256, 2) void gemm_kernel(
    const unsigned short* __restrict__ xs,   // [M] rows: 2048 bf16 in first 4KB of 8KB stride
    const unsigned short* __restrict__ wt,   // [N][K] bf16, 4KB rows
    const float* __restrict__ b1,
    float* __restrict__ hsum,
    const float* __restrict__ w2r,
    const float* __restrict__ c2,
    int* __restrict__ cnt,
    float* __restrict__ out) {
    __shared__ __align__(16) unsigned short lds[2 * 16384];  // 64KB: 2 bufs x (A 16KB | B 16KB)
    __shared__ int ticket_s;
    __shared__ float lg[64];

    const int t = threadIdx.x, lane = t & 63, wid = t >> 6;
    const int xcd = blockIdx.x & 7, i0 = blockIdx.x >> 3;
    const int n0 = (xcd >> 1) * BN;
    const int m0 = ((xcd & 1) * 64 + i0) * BM;
    const int mw = wid >> 1, nw = wid & 1;
    const int fr = lane & 15, kg = lane >> 4, fr7 = lane & 7;

    f32x4 acc[4][4];
#pragma unroll
    for (int i = 0; i < 4; ++i)
#pragma unroll
        for (int j = 0; j < 4; ++j) acc[i][j] = (f32x4){0.f, 0.f, 0.f, 0.f};

    int srow[4], sgo[4], ldso[4];
#pragma unroll
    for (int ii = 0; ii < 4; ++ii) {
        const int idx = wid * 4 + ii;
        const int o = (idx << 10) + (lane << 4);
        const int r = o >> 7, sl = (o >> 4) & 7;
        srow[ii] = r;
        sgo[ii]  = ((sl ^ (r & 7)) << 4);
        ldso[ii] = (idx << 10);
    }

    int aoff[4], boff[4];
#pragma unroll
    for (int f = 0; f < 4; ++f) {
        aoff[f] = (mw * 64 + f * 16 + fr) * 128;
        boff[f] = (nw * 64 + f * 16 + fr) * 128;
    }
    const char* xb = (const char*)xs;
    const char* wb = (const char*)wt;

    auto stage = [&](int bsel, int k0b) {
        char* base = (char*)lds + bsel * 32768;
#pragma unroll
        for (int ii = 0; ii < 4; ++ii) {
            const char* a = xb + (size_t)(m0 + srow[ii]) * 8192 + k0b + sgo[ii];
            const char* b = wb + (size_t)(n0 + srow[ii]) * 4096 + k0b + sgo[ii];
            gload_lds16(a, base +     0 + ldso[ii]);
            gload_lds16(b, base + 16384 + ldso[ii]);
        }
    };

    stage(0, 0);
    __syncthreads();             // tile 0 resident
    int buf = 0;
    for (int it = 0; it < 32; ++it) {
        if (it < 31) stage(buf ^ 1, (it + 1) << 7);   // issue next tile FIRST
        const char* ab = (const char*)lds + buf * 32768;
#pragma unroll
        for (int kk = 0; kk < 2; ++kk) {
            const int sw = ((kk * 4 + kg) ^ fr7) << 4;   // swizzled 16B k-slot
            bf16x8 ah[4], bh[4];
#pragma unroll
            for (int f = 0; f < 4; ++f) {
                ah[f] = *(const bf16x8*)(ab +     0 + aoff[f] + sw);
                bh[f] = *(const bf16x8*)(ab + 16384 + boff[f] + sw);
            }
#pragma unroll
            for (int i = 0; i < 4; ++i)
#pragma unroll
                for (int j = 0; j < 4; ++j)
                    acc[i][j] = __builtin_amdgcn_mfma_f32_16x16x32_bf16(ah[i], bh[j], acc[i][j], 0, 0, 0);
        }
        __syncthreads();   // single barrier per K-step
        buf ^= 1;
    }

    // Epilogue: y = acc + b1; h = exact GELU(y); per-column partial sums.
    float* red = (float*)lds;            // [wid*4+kg][64 cols]
    float pn[4];
#pragma unroll
    for (int j = 0; j < 4; ++j) pn[j] = 0.f;
#pragma unroll
    for (int j = 0; j < 4; ++j) {
        const float bb = b1[n0 + nw * 64 + j * 16 + fr];
#pragma unroll
        for (int i = 0; i < 4; ++i)
#pragma unroll
            for (int r = 0; r < 4; ++r) {
                const float y = acc[i][j][r] + bb;
                pn[j] += 0.5f * y * (1.f + erff(y * 0.70710678118654752f));
            }
    }
#pragma unroll
    for (int j = 0; j < 4; ++j)
        red[(wid * 4 + kg) * 64 + j * 16 + fr] = pn[j];
    __syncthreads();
    if (t < 128) {
        const int nw2 = t >> 6, cl = t & 63;
        float s2 = 0.f;
#pragma unroll
        for (int mw2 = 0; mw2 < 2; ++mw2)
#pragma unroll
            for (int g = 0; g < 4; ++g)
                s2 += red[((mw2 * 2 + nw2) * 4 + g) * 64 + cl];
        atomicAdd(&hsum[(m0 >> 11) * R_DIM + n0 + t], s2);
    }

    // ---- ticket: last-arriving block runs the finish phase ----
    __syncthreads();             // all hsum atomics of this block issued
    if (t == 0) {
        __threadfence();         // release: make our hsum adds visible first
        ticket_s = atomicAdd(cnt, 1);
    }
    __syncthreads();
    if (ticket_s != 511) return;

    __threadfence();             // acquire: see all 511 other blocks' adds
    float* hs = (float*)lds;          // 16KB
    float* wl = (float*)lds + 4096;   // 16KB
    for (int i = t; i < B_NUM * R_DIM; i += 256) {
        hs[i] = __hip_atomic_load(&hsum[i], __ATOMIC_RELAXED, __HIP_MEMORY_SCOPE_AGENT);
        wl[i] = w2r[i];
    }
    __syncthreads();

    // logits: 64 (b,e) pairs x 4 r-subgroups
    {
        const int p = t >> 2, sub = t & 3;
        const int b = p >> 3, e = p & 7;
        float s = 0.f;
        for (int r = sub; r < R_DIM; r += 4)
            s = fmaf(hs[b * R_DIM + r], wl[r * E_NUM + e], s);
        s += __shfl_down(s, 2, 4);
        s += __shfl_down(s, 1, 4);
        if (sub == 0) lg[p] = s + c2[e];
    }
    __syncthreads();
    if (t == 0) {
        int cb[8] = {0, 0, 0, 0, 0, 0, 0, 0};
        float loss = 0.f;
        for (int bb = 0; bb < 8; ++bb) {
            int best = 0;
            float bv = lg[bb * 8];
            for (int ee = 1; ee < 8; ++ee)
                if (lg[bb * 8 + ee] > bv) { bv = lg[bb * 8 + ee]; best = ee; }
            cb[best]++;
            for (int ee = 0; ee < 8; ++ee) {
                const float xv = lg[bb * 8 + ee];
                loss += fmaxf(xv, 0.f) + log1pf(expf(-fabsf(xv))) - (ee == best ? xv : 0.f);
            }
        }
        out[0] = loss * (1.f / 64.f);
        int ni = 0;
        for (int ee = 1; ee < 8; ++ee)
            if (cb[ee] > cb[ni]) ni = ee;   // first max == smallest on ties
        out[1] = (float)ni;
    }
}

extern "C" void kernel_launch(void* const* d_in, const int* in_sizes, int n_in,
                              void* d_out, int out_size, void* d_ws, size_t ws_size,
                              hipStream_t stream) {
    float* x           = (float*)d_in[0];   // normalized+bf16-packed in place
    const float* gamma = (const float*)d_in[1];
    const float* beta  = (const float*)d_in[2];
    const float* w1    = (const float*)d_in[3];
    const float* b1    = (const float*)d_in[4];
    const float* w2    = (const float*)d_in[5];
    const float* b2    = (const float*)d_in[6];
    const float* wr    = (const float*)d_in[7];
    const float* br    = (const float*)d_in[8];
    float* out = (float*)d_out;
    float* ws  = (float*)d_ws;

    float* hsum = ws;                                    // [0,4096) floats (zeroed by prep)
    float* w2r  = ws + 4096;                             // [4096,8192)
    float* c2   = ws + 8192;                             // [8192,8200)
    int*   cnt  = (int*)(ws + 8200);                     // ticket counter (zeroed by prep)
    unsigned short* wt = (unsigned short*)(ws + 8448);   // 1M ushort (2MB)

    prep_kernel<<<dim3(M_DIM + 1024 + 65 + 16), dim3(256), 0, stream>>>(
        x, gamma, beta, w1, w2, b2, wr, br, wt, w2r, c2, hsum, cnt);
    gemm_kernel<<<dim3(512), dim3(256), 0, stream>>>(
        (const unsigned short*)x, wt, b1, hsum, w2r, c2, cnt, out);
}